// Round 2
// baseline (9349.326 us; speedup 1.0000x reference)
//
#include <hip/hip_runtime.h>

#define HID 50
#define LAT 16
#define BLK 256   // 4 waves per block
#define NW  4     // waves per block

__device__ __forceinline__ float fast_tanh(float x) {
    // tanh(x) = 1 - 2/(exp(2x)+1); saturates correctly at +/-inf
    float e = __expf(2.0f * x);
    return 1.0f - 2.0f * __builtin_amdgcn_rcpf(e + 1.0f);
}

// Partial ODE func: this wave's NJ hidden units starting at j0.
// op[16] = sum_{j in slice} tanh(bo1[j] + z.Wo1[:,j]) * Wo2[j,:]  (+ wsel*bo2)
template<int NJ>
__device__ __forceinline__ void odef_part(const float* __restrict__ Wo1, const float* __restrict__ bo1,
                                          const float* __restrict__ Wo2, const float* __restrict__ bo2,
                                          int j0, float wsel,
                                          const float zin[LAT], float op[LAT]) {
    float th[NJ];
#pragma unroll
    for (int jj = 0; jj < NJ; jj++) th[jj] = bo1[j0 + jj];
#pragma unroll
    for (int i = 0; i < LAT; i++) {
        float zi = zin[i];
#pragma unroll
        for (int jj = 0; jj < NJ; jj++)
            th[jj] = __builtin_fmaf(zi, Wo1[i * HID + j0 + jj], th[jj]);
    }
#pragma unroll
    for (int jj = 0; jj < NJ; jj++) th[jj] = fast_tanh(th[jj]);
#pragma unroll
    for (int k = 0; k < LAT; k++) op[k] = wsel * bo2[k];
#pragma unroll
    for (int jj = 0; jj < NJ; jj++) {
        float tv = th[jj];
#pragma unroll
        for (int k = 0; k < LAT; k++)
            op[k] = __builtin_fmaf(tv, Wo2[(j0 + jj) * LAT + k], op[k]);
    }
}

// Partial decoder: y_partial = sum_{j in slice} relu(bd1[j] + z.Wd1[:,j]) * Wd2[j]
template<int NJ>
__device__ __forceinline__ float dec_part(const float* __restrict__ Wd1, const float* __restrict__ bd1,
                                          const float* __restrict__ Wd2,
                                          int j0, const float z[LAT]) {
    float h[NJ];
#pragma unroll
    for (int jj = 0; jj < NJ; jj++) h[jj] = bd1[j0 + jj];
#pragma unroll
    for (int i = 0; i < LAT; i++) {
        float zi = z[i];
#pragma unroll
        for (int jj = 0; jj < NJ; jj++)
            h[jj] = __builtin_fmaf(zi, Wd1[i * HID + j0 + jj], h[jj]);
    }
    float y = 0.0f;
#pragma unroll
    for (int jj = 0; jj < NJ; jj++)
        y = __builtin_fmaf(fmaxf(h[jj], 0.0f), Wd2[j0 + jj], y);
    return y;
}

__global__ void __launch_bounds__(BLK, 4)
node_kernel(const float* __restrict__ x0, const float* __restrict__ t,
            const float* __restrict__ We1, const float* __restrict__ be1,
            const float* __restrict__ We2, const float* __restrict__ be2,
            const float* __restrict__ Wo1, const float* __restrict__ bo1,
            const float* __restrict__ Wo2, const float* __restrict__ bo2,
            const float* __restrict__ Wd1, const float* __restrict__ bd1,
            const float* __restrict__ Wd2, const float* __restrict__ bd2,
            float* __restrict__ out, int B, int T) {
    // double-buffered reduce: [buf][w][k][lane]  (lane-contiguous -> bank-conflict-free)
    __shared__ float lds[2 * NW * LAT * 64];

    const int lane = threadIdx.x & 63;
    const int w    = threadIdx.x >> 6;     // wave id 0..3 (wave-uniform)
    const int b    = blockIdx.x * 64 + lane;
    const int j0   = w * 13;               // hidden slice start: 0,13,26,39
    const float wsel = (w == 0) ? 1.0f : 0.0f;

    // ---- Encoder (replicated in all 4 waves; one-time cost) ----
    float xa = x0[2 * b], xb = x0[2 * b + 1];
    float z[LAT];
#pragma unroll
    for (int k = 0; k < LAT; k++) z[k] = be2[k];
#pragma unroll
    for (int j = 0; j < HID; j++) {
        float h = __builtin_fmaf(xa, We1[j], __builtin_fmaf(xb, We1[HID + j], be1[j]));
        h = fmaxf(h, 0.0f);
#pragma unroll
        for (int k = 0; k < LAT; k++) z[k] = __builtin_fmaf(h, We2[j * LAT + k], z[k]);
    }

    int buf = 0;

    // ---- decode + emit helper (macro to keep regs tight) ----
#define DECODE_EMIT(row)                                                            \
    {                                                                               \
        float yp = (w < 3) ? dec_part<13>(Wd1, bd1, Wd2, j0, z)                     \
                           : dec_part<11>(Wd1, bd1, Wd2, j0, z);                    \
        yp += wsel * bd2[0];                                                        \
        float* base = lds + buf * (NW * LAT * 64);                                  \
        base[(w * LAT) * 64 + lane] = yp;                                           \
        __syncthreads();                                                            \
        if (w == 0) {                                                               \
            float y = base[(0 * LAT) * 64 + lane] + base[(1 * LAT) * 64 + lane]     \
                    + base[(2 * LAT) * 64 + lane] + base[(3 * LAT) * 64 + lane];    \
            out[(size_t)(row) * B + b] = y;                                         \
        }                                                                           \
        buf ^= 1;                                                                   \
    }

#define ODE_EXCHANGE(zin, o)                                                        \
    {                                                                               \
        float op[LAT];                                                              \
        if (w < 3) odef_part<13>(Wo1, bo1, Wo2, bo2, j0, wsel, zin, op);            \
        else       odef_part<11>(Wo1, bo1, Wo2, bo2, j0, wsel, zin, op);            \
        float* base = lds + buf * (NW * LAT * 64);                                  \
        _Pragma("unroll")                                                           \
        for (int k = 0; k < LAT; k++) base[(w * LAT + k) * 64 + lane] = op[k];      \
        __syncthreads();                                                            \
        _Pragma("unroll")                                                           \
        for (int k = 0; k < LAT; k++)                                               \
            o[k] = base[(0 * LAT + k) * 64 + lane] + base[(1 * LAT + k) * 64 + lane]\
                 + base[(2 * LAT + k) * 64 + lane] + base[(3 * LAT + k) * 64 + lane];\
        buf ^= 1;                                                                   \
    }

    // t = 0 output
    DECODE_EMIT(0);

    // ---- RK4 time stepping ----
    for (int s = 0; s < T - 1; s++) {
        float dt = t[s + 1] - t[s];
        float ksum[LAT], ztmp[LAT], o[LAT];

        ODE_EXCHANGE(z, o);                       // k1
#pragma unroll
        for (int i = 0; i < LAT; i++) {
            ksum[i] = o[i];
            ztmp[i] = __builtin_fmaf(0.5f * dt, o[i], z[i]);
        }
        ODE_EXCHANGE(ztmp, o);                    // k2
#pragma unroll
        for (int i = 0; i < LAT; i++) {
            ksum[i] = __builtin_fmaf(2.0f, o[i], ksum[i]);
            ztmp[i] = __builtin_fmaf(0.5f * dt, o[i], z[i]);
        }
        ODE_EXCHANGE(ztmp, o);                    // k3
#pragma unroll
        for (int i = 0; i < LAT; i++) {
            ksum[i] = __builtin_fmaf(2.0f, o[i], ksum[i]);
            ztmp[i] = __builtin_fmaf(dt, o[i], z[i]);
        }
        ODE_EXCHANGE(ztmp, o);                    // k4
        float c = dt * (1.0f / 6.0f);
#pragma unroll
        for (int i = 0; i < LAT; i++) z[i] = __builtin_fmaf(c, ksum[i] + o[i], z[i]);

        DECODE_EMIT(s + 1);
    }
#undef DECODE_EMIT
#undef ODE_EXCHANGE
}

extern "C" void kernel_launch(void* const* d_in, const int* in_sizes, int n_in,
                              void* d_out, int out_size, void* d_ws, size_t ws_size,
                              hipStream_t stream) {
    const float* x0  = (const float*)d_in[0];
    const float* t   = (const float*)d_in[1];
    const float* We1 = (const float*)d_in[2];
    const float* be1 = (const float*)d_in[3];
    const float* We2 = (const float*)d_in[4];
    const float* be2 = (const float*)d_in[5];
    const float* Wo1 = (const float*)d_in[6];
    const float* bo1 = (const float*)d_in[7];
    const float* Wo2 = (const float*)d_in[8];
    const float* bo2 = (const float*)d_in[9];
    const float* Wd1 = (const float*)d_in[10];
    const float* bd1 = (const float*)d_in[11];
    const float* Wd2 = (const float*)d_in[12];
    const float* bd2 = (const float*)d_in[13];
    float* out = (float*)d_out;

    int B = in_sizes[0] / 2;   // 65536
    int T = in_sizes[1];       // 100

    dim3 block(BLK);
    dim3 grid(B / 64);         // 1024 blocks, 64 batch elements each
    hipLaunchKernelGGL(node_kernel, grid, block, 0, stream,
                       x0, t, We1, be1, We2, be2, Wo1, bo1, Wo2, bo2,
                       Wd1, bd1, Wd2, bd2, out, B, T);
}

// Round 3
// 1903.809 us; speedup vs baseline: 4.9109x; 4.9109x over previous
//
#include <hip/hip_runtime.h>

#define HID 50
#define LAT 16
#define NW  4          // waves per block (hidden-dim split)
#define BLK (NW * 64)  // 256 threads, 64 batch elements per block

__device__ __forceinline__ float fast_tanh(float x) {
    // tanh(x) = 1 - 2/(exp(2x)+1); saturates correctly at +/-inf
    float e = __expf(2.0f * x);
    return 1.0f - 2.0f * __builtin_amdgcn_rcpf(e + 1.0f);
}

// Partial ODE func over NJ hidden units starting at wave-uniform j0.
// op[16] = wsel*bo2 + sum_{j in slice} tanh(bo1[j] + z.Wo1[:,j]) * Wo2[j,:]
template<int NJ>
__device__ __forceinline__ void odef_part(const float* __restrict__ Wo1, const float* __restrict__ bo1,
                                          const float* __restrict__ Wo2, const float* __restrict__ bo2,
                                          int j0, float wsel,
                                          const float zin[LAT], float op[LAT]) {
    const float* __restrict__ w1 = Wo1 + j0;        // uniform (j0 is SGPR)
    const float* __restrict__ w2 = Wo2 + j0 * LAT;  // uniform
    const float* __restrict__ b1 = bo1 + j0;
    float th[NJ];
#pragma unroll
    for (int jj = 0; jj < NJ; jj++) th[jj] = b1[jj];
#pragma unroll
    for (int i = 0; i < LAT; i++) {
        float zi = zin[i];
#pragma unroll
        for (int jj = 0; jj < NJ; jj++)
            th[jj] = __builtin_fmaf(zi, w1[i * HID + jj], th[jj]);
    }
#pragma unroll
    for (int jj = 0; jj < NJ; jj++) th[jj] = fast_tanh(th[jj]);
#pragma unroll
    for (int k = 0; k < LAT; k++) op[k] = wsel * bo2[k];
#pragma unroll
    for (int jj = 0; jj < NJ; jj++) {
        float tv = th[jj];
#pragma unroll
        for (int k = 0; k < LAT; k++)
            op[k] = __builtin_fmaf(tv, w2[jj * LAT + k], op[k]);
    }
}

// Partial decoder over NJ hidden units starting at wave-uniform j0.
template<int NJ>
__device__ __forceinline__ float dec_part(const float* __restrict__ Wd1, const float* __restrict__ bd1,
                                          const float* __restrict__ Wd2,
                                          int j0, const float z[LAT]) {
    const float* __restrict__ w1 = Wd1 + j0;  // uniform
    const float* __restrict__ b1 = bd1 + j0;
    const float* __restrict__ w2 = Wd2 + j0;
    float h[NJ];
#pragma unroll
    for (int jj = 0; jj < NJ; jj++) h[jj] = b1[jj];
#pragma unroll
    for (int i = 0; i < LAT; i++) {
        float zi = z[i];
#pragma unroll
        for (int jj = 0; jj < NJ; jj++)
            h[jj] = __builtin_fmaf(zi, w1[i * HID + jj], h[jj]);
    }
    float y = 0.0f;
#pragma unroll
    for (int jj = 0; jj < NJ; jj++)
        y = __builtin_fmaf(fmaxf(h[jj], 0.0f), w2[jj], y);
    return y;
}

__global__ void __launch_bounds__(BLK, 3)
node_kernel(const float* __restrict__ x0, const float* __restrict__ t,
            const float* __restrict__ We1, const float* __restrict__ be1,
            const float* __restrict__ We2, const float* __restrict__ be2,
            const float* __restrict__ Wo1, const float* __restrict__ bo1,
            const float* __restrict__ Wo2, const float* __restrict__ bo2,
            const float* __restrict__ Wd1, const float* __restrict__ bd1,
            const float* __restrict__ Wd2, const float* __restrict__ bd2,
            float* __restrict__ out, int B, int T) {
    // double-buffered reduce: [buf][w][k][lane]  (lane-contiguous -> 2-way alias, free)
    __shared__ float lds[2 * NW * LAT * 64];

    const int lane = threadIdx.x & 63;
    // readfirstlane forces the wave id into an SGPR -> weight addresses stay
    // uniform -> compiler emits s_load (round 2's per-lane global_load was the
    // 11.5 GB FETCH_SIZE disaster)
    const int wid  = __builtin_amdgcn_readfirstlane((int)(threadIdx.x >> 6));
    const int j0   = wid * 13;             // hidden slice start: 0,13,26,39
    const int b    = blockIdx.x * 64 + lane;
    const float wsel = (wid == 0) ? 1.0f : 0.0f;

    // ---- Encoder (replicated in all waves; one-time cost, uniform indices) ----
    float xa = x0[2 * b], xb = x0[2 * b + 1];
    float z[LAT];
#pragma unroll
    for (int k = 0; k < LAT; k++) z[k] = be2[k];
#pragma unroll
    for (int j = 0; j < HID; j++) {
        float h = __builtin_fmaf(xa, We1[j], __builtin_fmaf(xb, We1[HID + j], be1[j]));
        h = fmaxf(h, 0.0f);
#pragma unroll
        for (int k = 0; k < LAT; k++) z[k] = __builtin_fmaf(h, We2[j * LAT + k], z[k]);
    }

    int buf = 0;

#define DECODE_EMIT(row)                                                             \
    {                                                                                \
        float yp = (wid < 3) ? dec_part<13>(Wd1, bd1, Wd2, j0, z)                    \
                             : dec_part<11>(Wd1, bd1, Wd2, j0, z);                   \
        yp += wsel * bd2[0];                                                         \
        float* base = lds + buf * (NW * LAT * 64);                                   \
        base[(wid * LAT) * 64 + lane] = yp;                                          \
        __syncthreads();                                                             \
        if (wid == 0) {                                                              \
            float y = base[(0 * LAT) * 64 + lane] + base[(1 * LAT) * 64 + lane]      \
                    + base[(2 * LAT) * 64 + lane] + base[(3 * LAT) * 64 + lane];     \
            out[(size_t)(row) * B + b] = y;                                          \
        }                                                                            \
        buf ^= 1;                                                                    \
    }

#define ODE_EXCHANGE(zin, o)                                                         \
    {                                                                                \
        float op[LAT];                                                               \
        if (wid < 3) odef_part<13>(Wo1, bo1, Wo2, bo2, j0, wsel, zin, op);           \
        else         odef_part<11>(Wo1, bo1, Wo2, bo2, j0, wsel, zin, op);           \
        float* base = lds + buf * (NW * LAT * 64);                                   \
        _Pragma("unroll")                                                            \
        for (int k = 0; k < LAT; k++) base[(wid * LAT + k) * 64 + lane] = op[k];     \
        __syncthreads();                                                             \
        _Pragma("unroll")                                                            \
        for (int k = 0; k < LAT; k++)                                                \
            o[k] = base[(0 * LAT + k) * 64 + lane] + base[(1 * LAT + k) * 64 + lane] \
                 + base[(2 * LAT + k) * 64 + lane] + base[(3 * LAT + k) * 64 + lane];\
        buf ^= 1;                                                                    \
    }

    // t = 0 output
    DECODE_EMIT(0);

    // ---- RK4 time stepping ----
    for (int s = 0; s < T - 1; s++) {
        float dt = t[s + 1] - t[s];
        float ksum[LAT], ztmp[LAT], o[LAT];

        ODE_EXCHANGE(z, o);                       // k1
#pragma unroll
        for (int i = 0; i < LAT; i++) {
            ksum[i] = o[i];
            ztmp[i] = __builtin_fmaf(0.5f * dt, o[i], z[i]);
        }
        ODE_EXCHANGE(ztmp, o);                    // k2
#pragma unroll
        for (int i = 0; i < LAT; i++) {
            ksum[i] = __builtin_fmaf(2.0f, o[i], ksum[i]);
            ztmp[i] = __builtin_fmaf(0.5f * dt, o[i], z[i]);
        }
        ODE_EXCHANGE(ztmp, o);                    // k3
#pragma unroll
        for (int i = 0; i < LAT; i++) {
            ksum[i] = __builtin_fmaf(2.0f, o[i], ksum[i]);
            ztmp[i] = __builtin_fmaf(dt, o[i], z[i]);
        }
        ODE_EXCHANGE(ztmp, o);                    // k4
        float c = dt * (1.0f / 6.0f);
#pragma unroll
        for (int i = 0; i < LAT; i++) z[i] = __builtin_fmaf(c, ksum[i] + o[i], z[i]);

        DECODE_EMIT(s + 1);
    }
#undef DECODE_EMIT
#undef ODE_EXCHANGE
}

extern "C" void kernel_launch(void* const* d_in, const int* in_sizes, int n_in,
                              void* d_out, int out_size, void* d_ws, size_t ws_size,
                              hipStream_t stream) {
    const float* x0  = (const float*)d_in[0];
    const float* t   = (const float*)d_in[1];
    const float* We1 = (const float*)d_in[2];
    const float* be1 = (const float*)d_in[3];
    const float* We2 = (const float*)d_in[4];
    const float* be2 = (const float*)d_in[5];
    const float* Wo1 = (const float*)d_in[6];
    const float* bo1 = (const float*)d_in[7];
    const float* Wo2 = (const float*)d_in[8];
    const float* bo2 = (const float*)d_in[9];
    const float* Wd1 = (const float*)d_in[10];
    const float* bd1 = (const float*)d_in[11];
    const float* Wd2 = (const float*)d_in[12];
    const float* bd2 = (const float*)d_in[13];
    float* out = (float*)d_out;

    int B = in_sizes[0] / 2;   // 65536
    int T = in_sizes[1];       // 100

    dim3 block(BLK);
    dim3 grid(B / 64);         // 1024 blocks, 64 batch elements each
    hipLaunchKernelGGL(node_kernel, grid, block, 0, stream,
                       x0, t, We1, be1, We2, be2, Wo1, bo1, Wo2, bo2,
                       Wd1, bd1, Wd2, bd2, out, B, T);
}

// Round 4
// 636.274 us; speedup vs baseline: 14.6939x; 2.9921x over previous
//
#include <hip/hip_runtime.h>

#define HID 50
#define LAT 16
#define NW  4          // waves per block (independent waves, no barriers)
#define BLK (NW * 64)
#define MPW 16         // batch elements per wave (one MFMA M-tile)

typedef __attribute__((ext_vector_type(8))) short short8;  // 8 bf16 = 4 VGPRs
typedef __attribute__((ext_vector_type(4))) float f32x4;

#define MFMA16(a, b, c) __builtin_amdgcn_mfma_f32_16x16x32_bf16(a, b, c, 0, 0, 0)

// fp32 -> bf16 round-half-up (tie bias ~2^-16, negligible; values are bounded, no NaN/Inf)
__device__ __forceinline__ short f2bf(float f) {
    unsigned u = __builtin_bit_cast(unsigned, f);
    return (short)((u + 0x8000u) >> 16);
}

__device__ __forceinline__ float fast_tanh(float x) {
    // tanh(x) = 1 - 2/(exp(2x)+1); exact +/-1 saturation, tanh(0)=0 exact
    float e = __expf(2.0f * x);
    return 1.0f - 2.0f * __builtin_amdgcn_rcpf(e + 1.0f);
}

// B-frag for stage-1 GEMM: W[Kreal x 50] row-major, K padded 16->32.
// k==16 is the bias slot (A supplies 1.0 there); col n==50 carries satval at k==16
// so that act(h[.,50]) == 1.0 feeds the stage-2 bias row.
__device__ __forceinline__ short8 bfragK16(const float* __restrict__ W, const float* __restrict__ bias,
                                           int Kreal, int n, int quad, float satval) {
    short8 v;
#pragma unroll
    for (int j = 0; j < 8; j++) {
        int k = quad * 8 + j;
        float f = 0.0f;
        if (n < HID) {
            if (k < Kreal)      f = W[k * HID + n];
            else if (k == LAT)  f = bias[n];
        } else if (n == HID) {
            if (k == LAT)       f = satval;
        }
        v[j] = f2bf(f);
    }
    return v;
}

// B-frag for stage-2 GEMM: W[50 x 16] row-major, K padded 50->64 in 2 chunks of 32.
// k==50 is the bias row (A supplies 1.0 there via the satval column).
__device__ __forceinline__ short8 bfragK64(const float* __restrict__ W, const float* __restrict__ bias,
                                           int n, int quad, int chunk) {
    short8 v;
#pragma unroll
    for (int j = 0; j < 8; j++) {
        int k = chunk * 32 + quad * 8 + j;
        float f = 0.0f;
        if (k < HID)       f = W[k * LAT + n];
        else if (k == HID) f = bias[n];
        v[j] = f2bf(f);
    }
    return v;
}

// Decoder stage-2 B-frag: output dim 1 (col 0 only), Wd2[50], bias bd2 at k==50.
__device__ __forceinline__ short8 bfragDec2(const float* __restrict__ Wd2, float bd2s,
                                            int n, int quad, int chunk) {
    short8 v;
#pragma unroll
    for (int j = 0; j < 8; j++) {
        int k = chunk * 32 + quad * 8 + j;
        float f = 0.0f;
        if (n == 0) {
            if (k < HID)       f = Wd2[k];
            else if (k == HID) f = bd2s;
        }
        v[j] = f2bf(f);
    }
    return v;
}

__global__ void __launch_bounds__(BLK, 4)
node_kernel(const float* __restrict__ x0, const float* __restrict__ tt,
            const float* __restrict__ We1, const float* __restrict__ be1,
            const float* __restrict__ We2, const float* __restrict__ be2,
            const float* __restrict__ Wo1, const float* __restrict__ bo1,
            const float* __restrict__ Wo2, const float* __restrict__ bo2,
            const float* __restrict__ Wd1, const float* __restrict__ bd1,
            const float* __restrict__ Wd2, const float* __restrict__ bd2,
            float* __restrict__ out, int B, int T) {
    // per-wave private LDS: zbuf [16 m][32 k] bf16 (1KB) + hbuf [16 m][64 k] bf16 (2KB)
    __shared__ short lds_s[NW * 1536];

    const int lane = threadIdx.x & 63;
    const int wid  = __builtin_amdgcn_readfirstlane((int)(threadIdx.x >> 6));
    const int quad = lane >> 4;
    const int col  = lane & 15;
    const int wbase = blockIdx.x * (NW * MPW) + wid * MPW;

    short* zbuf = lds_s + wid * 1536;
    short* hbuf = zbuf + 512;

    // init zbuf: zero all 32 k-slots, then the k==16 bias slot = bf16(1.0).
    // cols 17..31 stay zero forever (transforms rewrite only cols 0..15).
    {
        int* zd = (int*)zbuf;
#pragma unroll
        for (int i = 0; i < 4; i++) zd[lane + 64 * i] = 0;
        if (lane < MPW) zbuf[lane * 32 + LAT] = (short)0x3F80;
    }

    // ---- persistent B-fragments (held in VGPRs for the whole kernel) ----
    short8 BWo1[4], BWd1[4];
    short8 BWo2[2], BWd2[2];
#pragma unroll
    for (int ti = 0; ti < 4; ti++) {
        BWo1[ti] = bfragK16(Wo1, bo1, LAT, col + 16 * ti, quad, 20.0f); // tanh(20)==1.0
        BWd1[ti] = bfragK16(Wd1, bd1, LAT, col + 16 * ti, quad, 1.0f);  // relu(1)==1.0
    }
#pragma unroll
    for (int c = 0; c < 2; c++) {
        BWo2[c] = bfragK64(Wo2, bo2, col, quad, c);
        BWd2[c] = bfragDec2(Wd2, bd2[0], col, quad, c);
    }
    const f32x4 zero4 = {0.0f, 0.0f, 0.0f, 0.0f};

    // ---- Encoder via MFMA (one-time; We-frags are transient) ----
    f32x4 z;
    {
        if (lane < MPW) {
            float xa = x0[2 * (wbase + lane)];
            float xb = x0[2 * (wbase + lane) + 1];
            unsigned pk = (unsigned)(unsigned short)f2bf(xa) |
                          ((unsigned)(unsigned short)f2bf(xb) << 16);
            *(unsigned*)(zbuf + lane * 32) = pk;  // cols 0,1; cols 2..15 are zero
        }
        short8 BWe1[4], BWe2[2];
#pragma unroll
        for (int ti = 0; ti < 4; ti++) BWe1[ti] = bfragK16(We1, be1, 2, col + 16 * ti, quad, 1.0f);
#pragma unroll
        for (int c = 0; c < 2; c++)    BWe2[c]  = bfragK64(We2, be2, col, quad, c);

        short8 az = *(const short8*)(zbuf + col * 32 + quad * 8);
        f32x4 h[4];
#pragma unroll
        for (int ti = 0; ti < 4; ti++) h[ti] = MFMA16(az, BWe1[ti], zero4);
#pragma unroll
        for (int ti = 0; ti < 4; ti++)
#pragma unroll
            for (int r = 0; r < 4; r++)
                hbuf[(quad * 4 + r) * 64 + col + 16 * ti] = f2bf(fmaxf(h[ti][r], 0.0f));
        short8 a0 = *(const short8*)(hbuf + col * 64 + quad * 8);
        short8 a1 = *(const short8*)(hbuf + col * 64 + 32 + quad * 8);
        z = MFMA16(a1, BWe2[1], MFMA16(a0, BWe2[0], zero4));
    }

    // ODE func: input A-frag (16 batch x K32 of z'), output C-layout f32x4
    auto odef = [&](short8 az) -> f32x4 {
        f32x4 hh[4];
#pragma unroll
        for (int ti = 0; ti < 4; ti++) hh[ti] = MFMA16(az, BWo1[ti], zero4);
#pragma unroll
        for (int ti = 0; ti < 4; ti++)
#pragma unroll
            for (int r = 0; r < 4; r++)
                hbuf[(quad * 4 + r) * 64 + col + 16 * ti] = f2bf(fast_tanh(hh[ti][r]));
        short8 a0 = *(const short8*)(hbuf + col * 64 + quad * 8);
        short8 a1 = *(const short8*)(hbuf + col * 64 + 32 + quad * 8);
        return MFMA16(a1, BWo2[1], MFMA16(a0, BWo2[0], zero4));
    };

    // write z' (C-layout regs) into zbuf cols 0..15, return A-frag
    auto z_to_afrag = [&](f32x4 zz) -> short8 {
#pragma unroll
        for (int r = 0; r < 4; r++) zbuf[(quad * 4 + r) * 32 + col] = f2bf(zz[r]);
        return *(const short8*)(zbuf + col * 32 + quad * 8);
    };

    // ---- main time loop: decode(z_s) -> out row s; RK4 -> z_{s+1} ----
    for (int s = 0;; s++) {
        short8 az = z_to_afrag(z);

        // decoder (shares az with k1)
        {
            f32x4 hd[4];
#pragma unroll
            for (int ti = 0; ti < 4; ti++) hd[ti] = MFMA16(az, BWd1[ti], zero4);
#pragma unroll
            for (int ti = 0; ti < 4; ti++)
#pragma unroll
                for (int r = 0; r < 4; r++)
                    hbuf[(quad * 4 + r) * 64 + col + 16 * ti] = f2bf(fmaxf(hd[ti][r], 0.0f));
            short8 a0 = *(const short8*)(hbuf + col * 64 + quad * 8);
            short8 a1 = *(const short8*)(hbuf + col * 64 + 32 + quad * 8);
            f32x4 y = MFMA16(a1, BWd2[1], MFMA16(a0, BWd2[0], zero4));
            if (col == 0)
                *(f32x4*)(out + (size_t)s * B + wbase + quad * 4) = y;  // rows quad*4+reg
        }

        if (s == T - 1) break;
        float dt = tt[s + 1] - tt[s];

        f32x4 k = odef(az);                      // k1
        f32x4 ksum = k;
        f32x4 ztmp = z + (0.5f * dt) * k;
        k = odef(z_to_afrag(ztmp));              // k2
        ksum += 2.0f * k;
        ztmp = z + (0.5f * dt) * k;
        k = odef(z_to_afrag(ztmp));              // k3
        ksum += 2.0f * k;
        ztmp = z + dt * k;
        k = odef(z_to_afrag(ztmp));              // k4
        z = z + (dt * (1.0f / 6.0f)) * (ksum + k);
    }
}

extern "C" void kernel_launch(void* const* d_in, const int* in_sizes, int n_in,
                              void* d_out, int out_size, void* d_ws, size_t ws_size,
                              hipStream_t stream) {
    const float* x0  = (const float*)d_in[0];
    const float* t   = (const float*)d_in[1];
    const float* We1 = (const float*)d_in[2];
    const float* be1 = (const float*)d_in[3];
    const float* We2 = (const float*)d_in[4];
    const float* be2 = (const float*)d_in[5];
    const float* Wo1 = (const float*)d_in[6];
    const float* bo1 = (const float*)d_in[7];
    const float* Wo2 = (const float*)d_in[8];
    const float* bo2 = (const float*)d_in[9];
    const float* Wd1 = (const float*)d_in[10];
    const float* bd1 = (const float*)d_in[11];
    const float* Wd2 = (const float*)d_in[12];
    const float* bd2 = (const float*)d_in[13];
    float* out = (float*)d_out;

    int B = in_sizes[0] / 2;   // 65536
    int T = in_sizes[1];       // 100

    dim3 block(BLK);
    dim3 grid(B / (NW * MPW)); // 1024 blocks, 64 batch elements each (16/wave)
    hipLaunchKernelGGL(node_kernel, grid, block, 0, stream,
                       x0, t, We1, be1, We2, be2, Wo1, bo1, Wo2, bo2,
                       Wd1, bd1, Wd2, bd2, out, B, T);
}